// Round 5
// baseline (229.442 us; speedup 1.0000x reference)
//
#include <hip/hip_runtime.h>
#include <hip/hip_bf16.h>

// Problem: single-head causal attention.
// x:[8,2048,1024] f32, Wk/Wq/Wv:[1024,64] f32 -> out:[8,2048,64] f32.
// Plan: (1) fused QKV projection -> bf16 q,k,v in d_ws (q pre-scaled by 0.125)
//       (2) flash-style causal attention, bf16 MFMA 16x16x32, fp32 accum.

typedef __attribute__((ext_vector_type(8))) __bf16 bf16x8;
typedef __attribute__((ext_vector_type(4))) float f32x4;

#define BT   16384   // B*T rows
#define TLEN 2048
#define NB   8

__device__ __forceinline__ ushort f2bf(float f) {
    unsigned u = __builtin_bit_cast(unsigned, f);
    unsigned r = (u + 0x7FFFu + ((u >> 16) & 1u)) >> 16;   // RNE to bf16
    return (ushort)r;
}

// ---------------- Kernel 1: fused QKV projection ----------------
// Block: 256 threads (4 waves), 64 rows of x. Each wave computes 16 rows x 64 cols
// for all three projections. K loop over 1024 in chunks of 64.
__global__ __launch_bounds__(256) void qkv_proj_kernel(
    const float* __restrict__ x, const float* __restrict__ Wk,
    const float* __restrict__ Wq, const float* __restrict__ Wv,
    ushort* __restrict__ kbuf, ushort* __restrict__ qbuf, ushort* __restrict__ vbuf)
{
    __shared__ __align__(16) ushort xs[64][72];       // x tile, bf16, +8 pad (144B row stride)
    __shared__ __align__(16) ushort wt[3][64][72];    // W^T tiles: wt[s][h][k_local]

    const int tid  = threadIdx.x;
    const int lane = tid & 63;
    const int w    = tid >> 6;
    const int m    = lane & 15;         // A-frag row / B-frag col
    const int ko   = (lane >> 4) * 8;   // A/B-frag k offset within 32-chunk
    const int rowb = (lane >> 4) * 4;   // C/D row base
    const int r0   = blockIdx.x * 64;

    f32x4 acc[3][4];
    #pragma unroll
    for (int s = 0; s < 3; ++s)
        #pragma unroll
        for (int nt = 0; nt < 4; ++nt) acc[s][nt] = (f32x4){0.f,0.f,0.f,0.f};

    const float* Ws[3] = {Wk, Wq, Wv};
    const int col4  = tid & 15;   // float4 column index (0..15)
    const int rbase = tid >> 4;   // 0..15

    for (int kc = 0; kc < 1024; kc += 64) {
        // stage x tile [64][64] f32 -> bf16 LDS
        #pragma unroll
        for (int it = 0; it < 4; ++it) {
            int row = rbase + it * 16;
            float4 v = *reinterpret_cast<const float4*>(
                &x[(size_t)(r0 + row) * 1024 + kc + col4 * 4]);
            ushort4 u;
            u.x = f2bf(v.x); u.y = f2bf(v.y); u.z = f2bf(v.z); u.w = f2bf(v.w);
            *reinterpret_cast<ushort4*>(&xs[row][col4 * 4]) = u;
        }
        // stage W tiles transposed: wt[s][h][k_local] = W[kc+k][h]
        #pragma unroll
        for (int s = 0; s < 3; ++s) {
            #pragma unroll
            for (int it = 0; it < 4; ++it) {
                int k = rbase + it * 16;
                float4 v = *reinterpret_cast<const float4*>(
                    &Ws[s][(size_t)(kc + k) * 64 + col4 * 4]);
                wt[s][col4 * 4 + 0][k] = f2bf(v.x);
                wt[s][col4 * 4 + 1][k] = f2bf(v.y);
                wt[s][col4 * 4 + 2][k] = f2bf(v.z);
                wt[s][col4 * 4 + 3][k] = f2bf(v.w);
            }
        }
        __syncthreads();

        #pragma unroll
        for (int kk = 0; kk < 64; kk += 32) {
            bf16x8 a = *reinterpret_cast<const bf16x8*>(&xs[w * 16 + m][kk + ko]);
            #pragma unroll
            for (int s = 0; s < 3; ++s) {
                #pragma unroll
                for (int nt = 0; nt < 4; ++nt) {
                    bf16x8 bb = *reinterpret_cast<const bf16x8*>(&wt[s][nt * 16 + m][kk + ko]);
                    acc[s][nt] = __builtin_amdgcn_mfma_f32_16x16x32_bf16(a, bb, acc[s][nt], 0, 0, 0);
                }
            }
        }
        __syncthreads();
    }

    ushort* outs[3]       = {kbuf, qbuf, vbuf};
    const float scales[3] = {1.0f, 0.125f, 1.0f};   // q pre-scaled by H^-0.5
    #pragma unroll
    for (int s = 0; s < 3; ++s) {
        #pragma unroll
        for (int nt = 0; nt < 4; ++nt) {
            #pragma unroll
            for (int j = 0; j < 4; ++j) {
                int r = r0 + w * 16 + rowb + j;     // C/D: row=(lane>>4)*4+reg
                int c = nt * 16 + m;                // C/D: col=lane&15
                outs[s][(size_t)r * 64 + c] = f2bf(acc[s][nt][j] * scales[s]);
            }
        }
    }
}

// ---------------- Kernel 2: flash causal attention ----------------
// Grid: (T/64, B). Block: 256 threads = 4 waves; wave w owns q rows [w*16, w*16+16).
__global__ __launch_bounds__(256) void attn_kernel(
    const ushort* __restrict__ qs, const ushort* __restrict__ ks,
    const ushort* __restrict__ vs, float* __restrict__ out)
{
    __shared__ __align__(16) ushort kt[64][72];       // K tile [kv][c]
    __shared__ __align__(16) ushort vt[64][72];       // V^T tile [h][kv]
    __shared__ __align__(16) ushort pl[4][16][72];    // per-wave P tile [qrow][kv]

    const int qt   = blockIdx.x;
    const int b    = blockIdx.y;
    const int tid  = threadIdx.x;
    const int lane = tid & 63;
    const int w    = tid >> 6;
    const int m    = lane & 15;
    const int ko   = (lane >> 4) * 8;
    const int rowb = (lane >> 4) * 4;
    const size_t base = (size_t)b * TLEN;

    // Q fragments (A operand), held in registers for the whole kernel
    bf16x8 qa[2];
    {
        size_t row_g = base + (size_t)qt * 64 + w * 16 + m;
        qa[0] = *reinterpret_cast<const bf16x8*>(&qs[row_g * 64 + 0 + ko]);
        qa[1] = *reinterpret_cast<const bf16x8*>(&qs[row_g * 64 + 32 + ko]);
    }

    f32x4 o[4];
    #pragma unroll
    for (int nt = 0; nt < 4; ++nt) o[nt] = (f32x4){0.f,0.f,0.f,0.f};
    float mrun[4] = {-1e30f, -1e30f, -1e30f, -1e30f};
    float lrun[4] = {0.f, 0.f, 0.f, 0.f};

    const int seg  = tid & 3;    // 16-col segment
    const int srow = tid >> 2;   // 0..63

    for (int t = 0; t <= qt; ++t) {
        // ---- stage K tile (row-major copy) ----
        const ushort* ksrc = &ks[(base + (size_t)t * 64 + srow) * 64 + seg * 16];
        *reinterpret_cast<uint4*>(&kt[srow][seg * 16 + 0]) = *reinterpret_cast<const uint4*>(ksrc);
        *reinterpret_cast<uint4*>(&kt[srow][seg * 16 + 8]) = *reinterpret_cast<const uint4*>(ksrc + 8);
        // ---- stage V tile transposed: vt[h][kv] ----
        const ushort* vsrc = &vs[(base + (size_t)t * 64 + srow) * 64 + seg * 16];
        union { uint4 v[2]; ushort u[16]; } tv;
        tv.v[0] = *reinterpret_cast<const uint4*>(vsrc);
        tv.v[1] = *reinterpret_cast<const uint4*>(vsrc + 8);
        #pragma unroll
        for (int i = 0; i < 16; ++i) vt[seg * 16 + i][srow] = tv.u[i];
        __syncthreads();

        // ---- scores: S = Q K^T (q pre-scaled) ----
        f32x4 s[4];
        #pragma unroll
        for (int nt = 0; nt < 4; ++nt) s[nt] = (f32x4){0.f,0.f,0.f,0.f};
        #pragma unroll
        for (int kk = 0; kk < 2; ++kk) {
            #pragma unroll
            for (int nt = 0; nt < 4; ++nt) {
                bf16x8 bb = *reinterpret_cast<const bf16x8*>(&kt[nt * 16 + m][kk * 32 + ko]);
                s[nt] = __builtin_amdgcn_mfma_f32_16x16x32_bf16(qa[kk], bb, s[nt], 0, 0, 0);
            }
        }

        // ---- causal mask (diagonal tile only) ----
        if (t == qt) {
            #pragma unroll
            for (int nt = 0; nt < 4; ++nt)
                #pragma unroll
                for (int j = 0; j < 4; ++j)
                    if (nt * 16 + m > w * 16 + rowb + j) s[nt][j] = -1e30f;
        }

        // ---- online softmax (rows distributed: 16-lane groups) ----
        #pragma unroll
        for (int j = 0; j < 4; ++j) {
            float mx = fmaxf(fmaxf(s[0][j], s[1][j]), fmaxf(s[2][j], s[3][j]));
            #pragma unroll
            for (int d = 1; d < 16; d <<= 1) mx = fmaxf(mx, __shfl_xor(mx, d, 64));
            float mnew = fmaxf(mrun[j], mx);
            float corr = __expf(mrun[j] - mnew);
            mrun[j] = mnew;
            float p0 = __expf(s[0][j] - mnew);
            float p1 = __expf(s[1][j] - mnew);
            float p2 = __expf(s[2][j] - mnew);
            float p3 = __expf(s[3][j] - mnew);
            float ps = p0 + p1 + p2 + p3;
            #pragma unroll
            for (int d = 1; d < 16; d <<= 1) ps += __shfl_xor(ps, d, 64);
            lrun[j] = lrun[j] * corr + ps;
            #pragma unroll
            for (int nt = 0; nt < 4; ++nt) o[nt][j] *= corr;
            pl[w][rowb + j][0 * 16 + m]  = f2bf(p0);
            pl[w][rowb + j][1 * 16 + m]  = f2bf(p1);
            pl[w][rowb + j][2 * 16 + m]  = f2bf(p2);
            pl[w][rowb + j][3 * 16 + m]  = f2bf(p3);
        }
        __syncthreads();   // drain P writes (re-layout across lanes within wave)

        // ---- O += P V ----
        #pragma unroll
        for (int kk = 0; kk < 2; ++kk) {
            bf16x8 pa = *reinterpret_cast<const bf16x8*>(&pl[w][m][kk * 32 + ko]);
            #pragma unroll
            for (int nt = 0; nt < 4; ++nt) {
                bf16x8 vb = *reinterpret_cast<const bf16x8*>(&vt[nt * 16 + m][kk * 32 + ko]);
                o[nt] = __builtin_amdgcn_mfma_f32_16x16x32_bf16(pa, vb, o[nt], 0, 0, 0);
            }
        }
        __syncthreads();   // protect kt/vt from next iteration's staging
    }

    // ---- epilogue: normalize and store f32 ----
    #pragma unroll
    for (int nt = 0; nt < 4; ++nt) {
        #pragma unroll
        for (int j = 0; j < 4; ++j) {
            size_t r = base + (size_t)qt * 64 + w * 16 + rowb + j;
            out[r * 64 + nt * 16 + m] = o[nt][j] / lrun[j];
        }
    }
}

extern "C" void kernel_launch(void* const* d_in, const int* in_sizes, int n_in,
                              void* d_out, int out_size, void* d_ws, size_t ws_size,
                              hipStream_t stream) {
    const float* x  = (const float*)d_in[0];
    const float* Wk = (const float*)d_in[1];
    const float* Wq = (const float*)d_in[2];
    const float* Wv = (const float*)d_in[3];
    float* out = (float*)d_out;

    // workspace: bf16 k | q | v, each BT*64 elems -> 6 MB total
    ushort* ws   = (ushort*)d_ws;
    ushort* kbuf = ws;
    ushort* qbuf = ws + (size_t)BT * 64;
    ushort* vbuf = ws + (size_t)2 * BT * 64;

    qkv_proj_kernel<<<dim3(BT / 64, 1, 1), 256, 0, stream>>>(x, Wk, Wq, Wv, kbuf, qbuf, vbuf);
    attn_kernel<<<dim3(TLEN / 64, NB, 1), 256, 0, stream>>>(qbuf, kbuf, vbuf, out);
}

// Round 6
// 186.599 us; speedup vs baseline: 1.2296x; 1.2296x over previous
//
#include <hip/hip_runtime.h>
#include <hip/hip_bf16.h>

// Single-head causal attention. x:[8,2048,1024] f32, W*:[1024,64] f32 -> out f32.
// v2: (0) wtrans: W -> bf16 W^T [192][1024], q-scale folded.
//     (1) qkv: register-only GEMM, 4-way K-split, no K-loop barriers.
//     (2) attn: 8-wave flash, kv split in 2 interleaved halves + LDS merge.

typedef __attribute__((ext_vector_type(8))) __bf16 bf16x8;
typedef __attribute__((ext_vector_type(4))) float f32x4;

#define BT   16384
#define TLEN 2048
#define NB   8

__device__ __forceinline__ ushort f2bf(float f) {
    unsigned u = __builtin_bit_cast(unsigned, f);
    unsigned r = (u + 0x7FFFu + ((u >> 16) & 1u)) >> 16;   // RNE to bf16
    return (ushort)r;
}

// ---------------- Kernel 0: W -> W^T bf16 (q-scale folded) ----------------
// wtb[n][k], n in [0,192): n<64 -> Wk, 64..127 -> Wq*0.125, 128..191 -> Wv.
__global__ void wtrans_kernel(const float* __restrict__ Wk, const float* __restrict__ Wq,
                              const float* __restrict__ Wv, ushort* __restrict__ wtb) {
    int n = blockIdx.x;                       // 192 blocks
    const float* W = (n < 64) ? Wk : (n < 128) ? Wq : Wv;
    float sc = (n >= 64 && n < 128) ? 0.125f : 1.0f;
    int h = n & 63;
    for (int k = threadIdx.x; k < 1024; k += 256)
        wtb[n * 1024 + k] = f2bf(W[(size_t)k * 64 + h] * sc);
}

// ---------------- Kernel 1: QKV projection, register-only ----------------
// Grid 512 x 512 threads. Block: rows R0..R0+32. 8 waves = (rowtile r in [0,2)) x (K-quarter h in [0,4)).
// Wave: 16 rows x 192 cols, K in [h*256, h*256+256), 8 MFMA k-steps, no barriers.
// Epilogue: LDS tree-reduce over quarters, bf16 store to kqv[3][BT][64].
__global__ __launch_bounds__(512, 3) void qkv_kernel2(
    const float* __restrict__ x, const ushort* __restrict__ wtb, ushort* __restrict__ kqv)
{
    __shared__ __align__(16) float ls_red[4][12][64][4];   // 48 KB

    const int tid  = threadIdx.x;
    const int lane = tid & 63;
    const int wv   = tid >> 6;
    const int r    = wv & 1;
    const int h    = wv >> 1;          // K-quarter
    const int m    = lane & 15;
    const int g    = lane >> 4;
    const int R0   = blockIdx.x * 32;
    const int arow = R0 + r * 16 + m;  // A-frag row

    f32x4 acc[12];
    #pragma unroll
    for (int nt = 0; nt < 12; ++nt) acc[nt] = (f32x4){0.f, 0.f, 0.f, 0.f};

    const float*  xp = &x[(size_t)arow * 1024 + h * 256 + g * 8];
    const ushort* wb = &wtb[h * 256 + g * 8 + (size_t)m * 1024];

    #pragma unroll
    for (int st = 0; st < 8; ++st) {
        float4 a0 = *reinterpret_cast<const float4*>(xp);
        float4 a1 = *reinterpret_cast<const float4*>(xp + 4);
        xp += 32;
        union { ushort u[8]; bf16x8 v; } av;
        av.u[0] = f2bf(a0.x); av.u[1] = f2bf(a0.y); av.u[2] = f2bf(a0.z); av.u[3] = f2bf(a0.w);
        av.u[4] = f2bf(a1.x); av.u[5] = f2bf(a1.y); av.u[6] = f2bf(a1.z); av.u[7] = f2bf(a1.w);
        #pragma unroll
        for (int nt = 0; nt < 12; ++nt) {
            bf16x8 b = *reinterpret_cast<const bf16x8*>(wb + (size_t)nt * 16 * 1024 + st * 32);
            acc[nt] = __builtin_amdgcn_mfma_f32_16x16x32_bf16(av.v, b, acc[nt], 0, 0, 0);
        }
    }

    // tree-reduce quarters: (h1->h0, h3->h2), then h2->h0
    if (h & 1) {
        int slot = (h >> 1) * 2 + r;
        #pragma unroll
        for (int nt = 0; nt < 12; ++nt)
            *reinterpret_cast<f32x4*>(&ls_red[slot][nt][lane][0]) = acc[nt];
    }
    __syncthreads();
    if (!(h & 1)) {
        int slot = h + r;   // h=0 -> r, h=2 -> 2+r
        #pragma unroll
        for (int nt = 0; nt < 12; ++nt)
            acc[nt] += *reinterpret_cast<const f32x4*>(&ls_red[slot][nt][lane][0]);
    }
    __syncthreads();
    if (h == 2) {
        #pragma unroll
        for (int nt = 0; nt < 12; ++nt)
            *reinterpret_cast<f32x4*>(&ls_red[r][nt][lane][0]) = acc[nt];
    }
    __syncthreads();
    if (h == 0) {
        #pragma unroll
        for (int nt = 0; nt < 12; ++nt) {
            acc[nt] += *reinterpret_cast<const f32x4*>(&ls_red[r][nt][lane][0]);
            int s = nt >> 2;
            int c = (nt & 3) * 16 + m;
            #pragma unroll
            for (int j = 0; j < 4; ++j) {
                size_t row = (size_t)R0 + r * 16 + g * 4 + j;   // C/D: row=(lane>>4)*4+j
                kqv[((size_t)s * BT + row) * 64 + c] = f2bf(acc[nt][j]);
            }
        }
    }
}

// ---------------- Kernel 2: flash causal attention, 8 waves ----------------
// Grid 256 x 512 threads (1D, XCD-swizzled: each XCD = one batch).
// Waves: wq = wv&3 owns q-rows [wq*16,+16); hf = wv>>2 processes kv tiles t = 2*it+hf.
// Each half keeps its own (m,l,O); merged in LDS at the end.
__global__ __launch_bounds__(512) void attn_kernel2(
    const ushort* __restrict__ qs, const ushort* __restrict__ ks,
    const ushort* __restrict__ vs, float* __restrict__ out)
{
    __shared__ __align__(16) ushort kt[2][64][72];
    __shared__ __align__(16) ushort vt[2][64][72];
    __shared__ __align__(16) ushort pl[8][16][72];

    // XCD-aware swizzle: 256 blocks, 8 XCDs -> xcd gets contiguous 32 = one batch
    const int bid = blockIdx.x;
    const int wg  = (bid & 7) * 32 + (bid >> 3);
    const int qt  = wg & 31;
    const int b   = wg >> 5;

    const int tid  = threadIdx.x;
    const int lane = tid & 63;
    const int wv   = tid >> 6;
    const int wq   = wv & 3;
    const int hf   = wv >> 2;
    const int m    = lane & 15;
    const int g    = lane >> 4;
    const int ko   = g * 8;
    const int rowb = g * 4;
    const size_t base = (size_t)b * TLEN;

    bf16x8 qa[2];
    {
        size_t row_g = base + (size_t)qt * 64 + wq * 16 + m;
        qa[0] = *reinterpret_cast<const bf16x8*>(&qs[row_g * 64 + 0 + ko]);
        qa[1] = *reinterpret_cast<const bf16x8*>(&qs[row_g * 64 + 32 + ko]);
    }

    f32x4 o[4];
    #pragma unroll
    for (int nt = 0; nt < 4; ++nt) o[nt] = (f32x4){0.f, 0.f, 0.f, 0.f};
    float mrun[4] = {-1e30f, -1e30f, -1e30f, -1e30f};
    float lrun[4] = {0.f, 0.f, 0.f, 0.f};

    const int hs   = tid >> 8;          // staging half
    const int seg  = (tid & 255) & 3;
    const int srow = (tid & 255) >> 2;

    const int nit = (qt >> 1) + 1;
    for (int it = 0; it < nit; ++it) {
        int ts = 2 * it + hs;
        if (ts <= qt) {
            const ushort* ksrc = &ks[(base + (size_t)ts * 64 + srow) * 64 + seg * 16];
            *reinterpret_cast<uint4*>(&kt[hs][srow][seg * 16 + 0]) = *reinterpret_cast<const uint4*>(ksrc);
            *reinterpret_cast<uint4*>(&kt[hs][srow][seg * 16 + 8]) = *reinterpret_cast<const uint4*>(ksrc + 8);
            const ushort* vsrc = &vs[(base + (size_t)ts * 64 + srow) * 64 + seg * 16];
            union { uint4 v[2]; ushort u[16]; } tv;
            tv.v[0] = *reinterpret_cast<const uint4*>(vsrc);
            tv.v[1] = *reinterpret_cast<const uint4*>(vsrc + 8);
            #pragma unroll
            for (int i = 0; i < 16; ++i) vt[hs][seg * 16 + i][srow] = tv.u[i];
        }
        __syncthreads();

        int t = 2 * it + hf;
        if (t <= qt) {
            f32x4 s[4];
            #pragma unroll
            for (int nt = 0; nt < 4; ++nt) s[nt] = (f32x4){0.f, 0.f, 0.f, 0.f};
            #pragma unroll
            for (int kk = 0; kk < 2; ++kk) {
                #pragma unroll
                for (int nt = 0; nt < 4; ++nt) {
                    bf16x8 bb = *reinterpret_cast<const bf16x8*>(&kt[hf][nt * 16 + m][kk * 32 + ko]);
                    s[nt] = __builtin_amdgcn_mfma_f32_16x16x32_bf16(qa[kk], bb, s[nt], 0, 0, 0);
                }
            }
            if (t == qt) {
                #pragma unroll
                for (int nt = 0; nt < 4; ++nt)
                    #pragma unroll
                    for (int j = 0; j < 4; ++j)
                        if (nt * 16 + m > wq * 16 + rowb + j) s[nt][j] = -1e30f;
            }
            #pragma unroll
            for (int j = 0; j < 4; ++j) {
                float mx = fmaxf(fmaxf(s[0][j], s[1][j]), fmaxf(s[2][j], s[3][j]));
                #pragma unroll
                for (int d = 1; d < 16; d <<= 1) mx = fmaxf(mx, __shfl_xor(mx, d, 64));
                float mnew = fmaxf(mrun[j], mx);
                float corr = __expf(mrun[j] - mnew);
                mrun[j] = mnew;
                float p0 = __expf(s[0][j] - mnew);
                float p1 = __expf(s[1][j] - mnew);
                float p2 = __expf(s[2][j] - mnew);
                float p3 = __expf(s[3][j] - mnew);
                float ps = p0 + p1 + p2 + p3;
                #pragma unroll
                for (int d = 1; d < 16; d <<= 1) ps += __shfl_xor(ps, d, 64);
                lrun[j] = lrun[j] * corr + ps;
                #pragma unroll
                for (int nt = 0; nt < 4; ++nt) o[nt][j] *= corr;
                pl[wv][rowb + j][0 * 16 + m] = f2bf(p0);
                pl[wv][rowb + j][1 * 16 + m] = f2bf(p1);
                pl[wv][rowb + j][2 * 16 + m] = f2bf(p2);
                pl[wv][rowb + j][3 * 16 + m] = f2bf(p3);
            }
            // P exchange is wave-local (pl[wv]); DS ops are in-order per wave.
            // Drain writes, then fence the scheduler (guide rule #18).
            asm volatile("s_waitcnt lgkmcnt(0)" ::: "memory");
            __builtin_amdgcn_sched_barrier(0);
            #pragma unroll
            for (int kk = 0; kk < 2; ++kk) {
                bf16x8 pa = *reinterpret_cast<const bf16x8*>(&pl[wv][m][kk * 32 + ko]);
                #pragma unroll
                for (int nt = 0; nt < 4; ++nt) {
                    bf16x8 vb = *reinterpret_cast<const bf16x8*>(&vt[hf][nt * 16 + m][kk * 32 + ko]);
                    o[nt] = __builtin_amdgcn_mfma_f32_16x16x32_bf16(pa, vb, o[nt], 0, 0, 0);
                }
            }
        }
        __syncthreads();   // protect kt/vt before next staging
    }

    // ---- merge halves: hf=1 publishes (O, m, l); hf=0 combines ----
    float* mg = reinterpret_cast<float*>(&kt[0][0][0]);   // [4][4][64] f32x4 = 16 KB
    float* st = reinterpret_cast<float*>(&vt[0][0][0]);   // [4][16][2]  = 512 B
    if (hf == 1) {
        #pragma unroll
        for (int nt = 0; nt < 4; ++nt)
            *reinterpret_cast<f32x4*>(&mg[((wq * 4 + nt) * 64 + lane) * 4]) = o[nt];
        if (m == 0) {
            #pragma unroll
            for (int j = 0; j < 4; ++j) {
                st[(wq * 16 + rowb + j) * 2 + 0] = mrun[j];
                st[(wq * 16 + rowb + j) * 2 + 1] = lrun[j];
            }
        }
    }
    __syncthreads();
    if (hf == 0) {
        float ea[4], eb[4], li[4];
        #pragma unroll
        for (int j = 0; j < 4; ++j) {
            float m1 = st[(wq * 16 + rowb + j) * 2 + 0];
            float l1 = st[(wq * 16 + rowb + j) * 2 + 1];
            float mm = fmaxf(mrun[j], m1);
            ea[j] = __expf(mrun[j] - mm);
            eb[j] = __expf(m1 - mm);
            li[j] = 1.0f / (lrun[j] * ea[j] + l1 * eb[j]);
        }
        #pragma unroll
        for (int nt = 0; nt < 4; ++nt) {
            f32x4 ob = *reinterpret_cast<const f32x4*>(&mg[((wq * 4 + nt) * 64 + lane) * 4]);
            #pragma unroll
            for (int j = 0; j < 4; ++j) {
                size_t rrow = base + (size_t)qt * 64 + wq * 16 + rowb + j;
                out[rrow * 64 + nt * 16 + m] = (o[nt][j] * ea[j] + ob[j] * eb[j]) * li[j];
            }
        }
    }
}

extern "C" void kernel_launch(void* const* d_in, const int* in_sizes, int n_in,
                              void* d_out, int out_size, void* d_ws, size_t ws_size,
                              hipStream_t stream) {
    const float* x  = (const float*)d_in[0];
    const float* Wk = (const float*)d_in[1];
    const float* Wq = (const float*)d_in[2];
    const float* Wv = (const float*)d_in[3];
    float* out = (float*)d_out;

    // ws: kqv bf16 [3][BT][64] (6 MB) | W^T bf16 [192][1024] (384 KB)
    ushort* ws   = (ushort*)d_ws;
    ushort* kqv  = ws;
    ushort* kbuf = ws;
    ushort* qbuf = ws + (size_t)BT * 64;
    ushort* vbuf = ws + (size_t)2 * BT * 64;
    ushort* wtb  = ws + (size_t)3 * BT * 64;

    wtrans_kernel<<<dim3(192), 256, 0, stream>>>(Wk, Wq, Wv, wtb);
    qkv_kernel2<<<dim3(512), 512, 0, stream>>>(x, wtb, kqv);
    attn_kernel2<<<dim3(256), 512, 0, stream>>>(qbuf, kbuf, vbuf, out);
}

// Round 7
// 167.242 us; speedup vs baseline: 1.3719x; 1.1157x over previous
//
#include <hip/hip_runtime.h>
#include <hip/hip_bf16.h>

// Single-head causal attention. x:[8,2048,1024] f32, W*:[1024,64] f32 -> out f32.
// v3: (0) wtrans: coalesced W -> bf16 W^T [192][1024], q-scale folded.
//     (1) qkv: register-only GEMM, 32-row waves, 4-way K-split, HW cvt, prefetch.
//     (2) attn: 8-wave flash, kv split in 2 interleaved halves + LDS merge (unchanged).

typedef __attribute__((ext_vector_type(8))) __bf16 bf16x8;
typedef __attribute__((ext_vector_type(4))) float f32x4;

#define BT   16384
#define TLEN 2048
#define NB   8

__device__ __forceinline__ ushort f2bf(float f) {
    __hip_bfloat16 h = __float2bfloat16(f);     // RNE; compiler emits v_cvt_pk_bf16_f32
    return __builtin_bit_cast(ushort, h);
}

// ---------------- Kernel 0: W -> W^T bf16 (q-scale folded), coalesced reads ----
// wtb[n][k], n in [0,192): n<64 -> Wk, 64..127 -> Wq*0.125, 128..191 -> Wv.
__global__ void wtrans_kernel(const float* __restrict__ Wk, const float* __restrict__ Wq,
                              const float* __restrict__ Wv, ushort* __restrict__ wtb) {
    int idx = blockIdx.x * 256 + threadIdx.x;   // 192 blocks -> 49152 threads, 4 elems each
    int e   = idx * 4;                          // flat over [3][1024][64]
    int s   = e >> 16;
    int rem = e & 65535;
    int k   = rem >> 6;
    int h   = rem & 63;                         // multiple of 4
    const float* W = (s == 0) ? Wk : (s == 1) ? Wq : Wv;
    float sc = (s == 1) ? 0.125f : 1.0f;
    float4 v = *reinterpret_cast<const float4*>(&W[(size_t)k * 64 + h]);
    wtb[(size_t)(s * 64 + h + 0) * 1024 + k] = f2bf(v.x * sc);
    wtb[(size_t)(s * 64 + h + 1) * 1024 + k] = f2bf(v.y * sc);
    wtb[(size_t)(s * 64 + h + 2) * 1024 + k] = f2bf(v.z * sc);
    wtb[(size_t)(s * 64 + h + 3) * 1024 + k] = f2bf(v.w * sc);
}

// ---------------- Kernel 1: QKV projection, register-only, 32-row waves -------
// Grid 512 x 256 threads. Block rows R0..R0+32. 4 waves = 4 K-quarters.
// Wave: 32 rows (2 A-frags) x 192 cols (12 B-tiles) over K in [h*256,+256), 8 k-steps.
// Epilogue: LDS tree-reduce over quarters, bf16 store to kqv[3][BT][64].
__global__ __launch_bounds__(256, 2) void qkv_kernel3(
    const float* __restrict__ x, const ushort* __restrict__ wtb, ushort* __restrict__ kqv)
{
    __shared__ __align__(16) f32x4 red[2][24][64];   // 48 KB, epilogue only

    const int tid  = threadIdx.x;
    const int lane = tid & 63;
    const int h    = tid >> 6;          // K-quarter
    const int m    = lane & 15;
    const int g    = lane >> 4;
    const int R0   = blockIdx.x * 32;

    f32x4 acc[24];
    #pragma unroll
    for (int i = 0; i < 24; ++i) acc[i] = (f32x4){0.f, 0.f, 0.f, 0.f};

    const float*  xp0 = &x[(size_t)(R0 + m)      * 1024 + h * 256 + g * 8];
    const float*  xp1 = &x[(size_t)(R0 + 16 + m) * 1024 + h * 256 + g * 8];
    const ushort* wb  = &wtb[(size_t)m * 1024 + h * 256 + g * 8];

    float4 xa0a = *reinterpret_cast<const float4*>(xp0);
    float4 xa0b = *reinterpret_cast<const float4*>(xp0 + 4);
    float4 xa1a = *reinterpret_cast<const float4*>(xp1);
    float4 xa1b = *reinterpret_cast<const float4*>(xp1 + 4);

    #pragma unroll
    for (int st = 0; st < 8; ++st) {
        float4 xn0a, xn0b, xn1a, xn1b;
        if (st < 7) {
            xn0a = *reinterpret_cast<const float4*>(xp0 + (st + 1) * 32);
            xn0b = *reinterpret_cast<const float4*>(xp0 + (st + 1) * 32 + 4);
            xn1a = *reinterpret_cast<const float4*>(xp1 + (st + 1) * 32);
            xn1b = *reinterpret_cast<const float4*>(xp1 + (st + 1) * 32 + 4);
        }
        union { ushort u[8]; bf16x8 v; } a0, a1;
        a0.u[0] = f2bf(xa0a.x); a0.u[1] = f2bf(xa0a.y); a0.u[2] = f2bf(xa0a.z); a0.u[3] = f2bf(xa0a.w);
        a0.u[4] = f2bf(xa0b.x); a0.u[5] = f2bf(xa0b.y); a0.u[6] = f2bf(xa0b.z); a0.u[7] = f2bf(xa0b.w);
        a1.u[0] = f2bf(xa1a.x); a1.u[1] = f2bf(xa1a.y); a1.u[2] = f2bf(xa1a.z); a1.u[3] = f2bf(xa1a.w);
        a1.u[4] = f2bf(xa1b.x); a1.u[5] = f2bf(xa1b.y); a1.u[6] = f2bf(xa1b.z); a1.u[7] = f2bf(xa1b.w);
        #pragma unroll
        for (int nt = 0; nt < 12; ++nt) {
            bf16x8 b = *reinterpret_cast<const bf16x8*>(wb + (size_t)nt * 16 * 1024 + st * 32);
            acc[nt]      = __builtin_amdgcn_mfma_f32_16x16x32_bf16(a0.v, b, acc[nt],      0, 0, 0);
            acc[12 + nt] = __builtin_amdgcn_mfma_f32_16x16x32_bf16(a1.v, b, acc[12 + nt], 0, 0, 0);
        }
        xa0a = xn0a; xa0b = xn0b; xa1a = xn1a; xa1b = xn1b;
    }

    // ---- reduce the 4 K-quarters: h1->h0, h3->h2, then h2->h0 ----
    if (h == 1 || h == 3) {
        #pragma unroll
        for (int i = 0; i < 24; ++i) red[h >> 1][i][lane] = acc[i];
    }
    __syncthreads();
    if (h == 0 || h == 2) {
        #pragma unroll
        for (int i = 0; i < 24; ++i) acc[i] += red[h >> 1][i][lane];
    }
    __syncthreads();
    if (h == 2) {
        #pragma unroll
        for (int i = 0; i < 24; ++i) red[0][i][lane] = acc[i];
    }
    __syncthreads();
    if (h == 0) {
        #pragma unroll
        for (int f = 0; f < 2; ++f) {
            #pragma unroll
            for (int nt = 0; nt < 12; ++nt) {
                f32x4 a = acc[f * 12 + nt] + red[0][f * 12 + nt][lane];
                int s = nt >> 2;
                int c = (nt & 3) * 16 + m;
                #pragma unroll
                for (int j = 0; j < 4; ++j) {
                    size_t row = (size_t)R0 + f * 16 + g * 4 + j;   // C/D: row=(lane>>4)*4+j
                    kqv[((size_t)s * BT + row) * 64 + c] = f2bf(a[j]);
                }
            }
        }
    }
}

// ---------------- Kernel 2: flash causal attention, 8 waves (unchanged) -------
__global__ __launch_bounds__(512) void attn_kernel2(
    const ushort* __restrict__ qs, const ushort* __restrict__ ks,
    const ushort* __restrict__ vs, float* __restrict__ out)
{
    __shared__ __align__(16) ushort kt[2][64][72];
    __shared__ __align__(16) ushort vt[2][64][72];
    __shared__ __align__(16) ushort pl[8][16][72];

    const int bid = blockIdx.x;
    const int wg  = (bid & 7) * 32 + (bid >> 3);
    const int qt  = wg & 31;
    const int b   = wg >> 5;

    const int tid  = threadIdx.x;
    const int lane = tid & 63;
    const int wv   = tid >> 6;
    const int wq   = wv & 3;
    const int hf   = wv >> 2;
    const int m    = lane & 15;
    const int g    = lane >> 4;
    const int ko   = g * 8;
    const int rowb = g * 4;
    const size_t base = (size_t)b * TLEN;

    bf16x8 qa[2];
    {
        size_t row_g = base + (size_t)qt * 64 + wq * 16 + m;
        qa[0] = *reinterpret_cast<const bf16x8*>(&qs[row_g * 64 + 0 + ko]);
        qa[1] = *reinterpret_cast<const bf16x8*>(&qs[row_g * 64 + 32 + ko]);
    }

    f32x4 o[4];
    #pragma unroll
    for (int nt = 0; nt < 4; ++nt) o[nt] = (f32x4){0.f, 0.f, 0.f, 0.f};
    float mrun[4] = {-1e30f, -1e30f, -1e30f, -1e30f};
    float lrun[4] = {0.f, 0.f, 0.f, 0.f};

    const int hs   = tid >> 8;
    const int seg  = (tid & 255) & 3;
    const int srow = (tid & 255) >> 2;

    const int nit = (qt >> 1) + 1;
    for (int it = 0; it < nit; ++it) {
        int ts = 2 * it + hs;
        if (ts <= qt) {
            const ushort* ksrc = &ks[(base + (size_t)ts * 64 + srow) * 64 + seg * 16];
            *reinterpret_cast<uint4*>(&kt[hs][srow][seg * 16 + 0]) = *reinterpret_cast<const uint4*>(ksrc);
            *reinterpret_cast<uint4*>(&kt[hs][srow][seg * 16 + 8]) = *reinterpret_cast<const uint4*>(ksrc + 8);
            const ushort* vsrc = &vs[(base + (size_t)ts * 64 + srow) * 64 + seg * 16];
            union { uint4 v[2]; ushort u[16]; } tv;
            tv.v[0] = *reinterpret_cast<const uint4*>(vsrc);
            tv.v[1] = *reinterpret_cast<const uint4*>(vsrc + 8);
            #pragma unroll
            for (int i = 0; i < 16; ++i) vt[hs][seg * 16 + i][srow] = tv.u[i];
        }
        __syncthreads();

        int t = 2 * it + hf;
        if (t <= qt) {
            f32x4 s[4];
            #pragma unroll
            for (int nt = 0; nt < 4; ++nt) s[nt] = (f32x4){0.f, 0.f, 0.f, 0.f};
            #pragma unroll
            for (int kk = 0; kk < 2; ++kk) {
                #pragma unroll
                for (int nt = 0; nt < 4; ++nt) {
                    bf16x8 bb = *reinterpret_cast<const bf16x8*>(&kt[hf][nt * 16 + m][kk * 32 + ko]);
                    s[nt] = __builtin_amdgcn_mfma_f32_16x16x32_bf16(qa[kk], bb, s[nt], 0, 0, 0);
                }
            }
            if (t == qt) {
                #pragma unroll
                for (int nt = 0; nt < 4; ++nt)
                    #pragma unroll
                    for (int j = 0; j < 4; ++j)
                        if (nt * 16 + m > wq * 16 + rowb + j) s[nt][j] = -1e30f;
            }
            #pragma unroll
            for (int j = 0; j < 4; ++j) {
                float mx = fmaxf(fmaxf(s[0][j], s[1][j]), fmaxf(s[2][j], s[3][j]));
                #pragma unroll
                for (int d = 1; d < 16; d <<= 1) mx = fmaxf(mx, __shfl_xor(mx, d, 64));
                float mnew = fmaxf(mrun[j], mx);
                float corr = __expf(mrun[j] - mnew);
                mrun[j] = mnew;
                float p0 = __expf(s[0][j] - mnew);
                float p1 = __expf(s[1][j] - mnew);
                float p2 = __expf(s[2][j] - mnew);
                float p3 = __expf(s[3][j] - mnew);
                float ps = p0 + p1 + p2 + p3;
                #pragma unroll
                for (int d = 1; d < 16; d <<= 1) ps += __shfl_xor(ps, d, 64);
                lrun[j] = lrun[j] * corr + ps;
                #pragma unroll
                for (int nt = 0; nt < 4; ++nt) o[nt][j] *= corr;
                pl[wv][rowb + j][0 * 16 + m] = f2bf(p0);
                pl[wv][rowb + j][1 * 16 + m] = f2bf(p1);
                pl[wv][rowb + j][2 * 16 + m] = f2bf(p2);
                pl[wv][rowb + j][3 * 16 + m] = f2bf(p3);
            }
            asm volatile("s_waitcnt lgkmcnt(0)" ::: "memory");
            __builtin_amdgcn_sched_barrier(0);
            #pragma unroll
            for (int kk = 0; kk < 2; ++kk) {
                bf16x8 pa = *reinterpret_cast<const bf16x8*>(&pl[wv][m][kk * 32 + ko]);
                #pragma unroll
                for (int nt = 0; nt < 4; ++nt) {
                    bf16x8 vb = *reinterpret_cast<const bf16x8*>(&vt[hf][nt * 16 + m][kk * 32 + ko]);
                    o[nt] = __builtin_amdgcn_mfma_f32_16x16x32_bf16(pa, vb, o[nt], 0, 0, 0);
                }
            }
        }
        __syncthreads();
    }

    float* mg = reinterpret_cast<float*>(&kt[0][0][0]);
    float* st = reinterpret_cast<float*>(&vt[0][0][0]);
    if (hf == 1) {
        #pragma unroll
        for (int nt = 0; nt < 4; ++nt)
            *reinterpret_cast<f32x4*>(&mg[((wq * 4 + nt) * 64 + lane) * 4]) = o[nt];
        if (m == 0) {
            #pragma unroll
            for (int j = 0; j < 4; ++j) {
                st[(wq * 16 + rowb + j) * 2 + 0] = mrun[j];
                st[(wq * 16 + rowb + j) * 2 + 1] = lrun[j];
            }
        }
    }
    __syncthreads();
    if (hf == 0) {
        float ea[4], eb[4], li[4];
        #pragma unroll
        for (int j = 0; j < 4; ++j) {
            float m1 = st[(wq * 16 + rowb + j) * 2 + 0];
            float l1 = st[(wq * 16 + rowb + j) * 2 + 1];
            float mm = fmaxf(mrun[j], m1);
            ea[j] = __expf(mrun[j] - mm);
            eb[j] = __expf(m1 - mm);
            li[j] = 1.0f / (lrun[j] * ea[j] + l1 * eb[j]);
        }
        #pragma unroll
        for (int nt = 0; nt < 4; ++nt) {
            f32x4 ob = *reinterpret_cast<const f32x4*>(&mg[((wq * 4 + nt) * 64 + lane) * 4]);
            #pragma unroll
            for (int j = 0; j < 4; ++j) {
                size_t rrow = base + (size_t)qt * 64 + wq * 16 + rowb + j;
                out[rrow * 64 + nt * 16 + m] = (o[nt][j] * ea[j] + ob[j] * eb[j]) * li[j];
            }
        }
    }
}

extern "C" void kernel_launch(void* const* d_in, const int* in_sizes, int n_in,
                              void* d_out, int out_size, void* d_ws, size_t ws_size,
                              hipStream_t stream) {
    const float* x  = (const float*)d_in[0];
    const float* Wk = (const float*)d_in[1];
    const float* Wq = (const float*)d_in[2];
    const float* Wv = (const float*)d_in[3];
    float* out = (float*)d_out;

    // ws: kqv bf16 [3][BT][64] (6 MB) | W^T bf16 [192][1024] (384 KB)
    ushort* ws   = (ushort*)d_ws;
    ushort* kqv  = ws;
    ushort* kbuf = ws;
    ushort* qbuf = ws + (size_t)BT * 64;
    ushort* vbuf = ws + (size_t)2 * BT * 64;
    ushort* wtb  = ws + (size_t)3 * BT * 64;

    wtrans_kernel<<<dim3(192), 256, 0, stream>>>(Wk, Wq, Wv, wtb);
    qkv_kernel3<<<dim3(512), 256, 0, stream>>>(x, wtb, kqv);
    attn_kernel2<<<dim3(256), 512, 0, stream>>>(qbuf, kbuf, vbuf, out);
}